// Round 9
// baseline (565.503 us; speedup 1.0000x reference)
//
#include <hip/hip_runtime.h>
#include <hip/hip_bf16.h>
#include <stdint.h>

// Problem constants: B=4,S=2048 -> T=8192, D=1024, H=2048, E=8, topk=2
#define T_TOK   8192
#define D_DIM   1024
#define H_DIM   2048
#define E_EXP   8
#define NP2     4096                    // interleaved w1/w2 rows = 2*H
#define BM      256                     // GEMM M-tile; expert regions 256-aligned
#define CAP     (2*T_TOK + E_EXP*BM)    // 18432 padded slots
#define MAXMB   (CAP/BM)                // 72 max m-blocks

using f32x4 = __attribute__((ext_vector_type(4))) float;
using s16x8 = __attribute__((ext_vector_type(8))) short;   // 8 bf16 (MFMA A/B frag)

__device__ __forceinline__ short bf16_of(float f) {
  union { float f; unsigned u; } v; v.f = f;
  unsigned r = v.u + 0x7FFFu + ((v.u >> 16) & 1u);          // RNE
  return (short)(r >> 16);
}
__device__ __forceinline__ float f_of_bf16(short s) {
  union { unsigned u; float f; } v; v.u = ((unsigned)(unsigned short)s) << 16;
  return v.f;
}

__device__ __forceinline__ void gload16(const void* g, void* l) {
  __builtin_amdgcn_global_load_lds(
      (const __attribute__((address_space(1))) unsigned int*)g,
      (__attribute__((address_space(3))) unsigned int*)l, 16, 0, 0);
}

// ---------------- gating (no atomics) ----------------
__global__ __launch_bounds__(256) void gate_kernel(const float* __restrict__ x,
                                                   const float* __restrict__ gw,
                                                   int* __restrict__ tok_e,
                                                   float* __restrict__ gatew) {
  __shared__ float g[E_EXP * D_DIM];               // 32 KiB
  int tid = threadIdx.x;
  for (int i = tid; i < E_EXP * 256; i += 256)
    ((f32x4*)g)[i] = ((const f32x4*)gw)[i];
  __syncthreads();
  int w = tid >> 6, lane = tid & 63;
  int t = blockIdx.x * 4 + w;
  float acc[E_EXP] = {};
  const f32x4* xrow = (const f32x4*)(x + (size_t)t * D_DIM);
#pragma unroll
  for (int i = 0; i < 4; ++i) {
    f32x4 xv = xrow[lane + 64 * i];
#pragma unroll
    for (int e = 0; e < E_EXP; ++e) {
      f32x4 gv = ((const f32x4*)g)[e * 256 + lane + 64 * i];
      acc[e] += xv[0] * gv[0] + xv[1] * gv[1] + xv[2] * gv[2] + xv[3] * gv[3];
    }
  }
#pragma unroll
  for (int e = 0; e < E_EXP; ++e)
#pragma unroll
    for (int off = 1; off < 64; off <<= 1)
      acc[e] += __shfl_xor(acc[e], off);
  if (lane == 0) {
    int i0 = 0; float v0 = acc[0];
    for (int e = 1; e < E_EXP; ++e) if (acc[e] > v0) { v0 = acc[e]; i0 = e; }  // ties: lower idx
    int i1 = -1; float v1 = -1e30f;
    for (int e = 0; e < E_EXP; ++e) if (e != i0 && acc[e] > v1) { v1 = acc[e]; i1 = e; }
    float z = __expf(v1 - v0);
    tok_e[2 * t] = i0; tok_e[2 * t + 1] = i1;
    gatew[2 * t] = 1.f / (1.f + z); gatew[2 * t + 1] = z / (1.f + z);
  }
}

// ---------------- histogram: ballot -> LDS -> 8 atomics/block ----------
__global__ __launch_bounds__(256) void hist_kernel(const int* __restrict__ tok_e,
                                                   int* __restrict__ counts) {
  __shared__ int bc[E_EXP];
  const int tid = threadIdx.x, lane = tid & 63;
  if (tid < E_EXP) bc[tid] = 0;
  __syncthreads();
  const int4 v = ((const int4*)tok_e)[blockIdx.x * 256 + tid];   // 4 entries/thread
#pragma unroll
  for (int e = 0; e < E_EXP; ++e) {
    int cnt = __popcll(__ballot(v.x == e)) + __popcll(__ballot(v.y == e)) +
              __popcll(__ballot(v.z == e)) + __popcll(__ballot(v.w == e));
    if (lane == 0 && cnt) atomicAdd(&bc[e], cnt);
  }
  __syncthreads();
  if (tid < E_EXP && bc[tid]) atomicAdd(&counts[tid], bc[tid]);
}

// ---------------- routing metadata ----------------
__global__ void scan_kernel(const int* __restrict__ counts, int* __restrict__ off,
                            int* __restrict__ mb2e, int* __restrict__ mb2row) {
  if (threadIdx.x == 0 && blockIdx.x == 0) {
    int acc = 0, mb = 0;
    for (int e = 0; e < E_EXP; ++e) {
      off[e] = acc;
      int nb = (counts[e] + BM - 1) / BM;
      for (int b = 0; b < nb; ++b) { mb2e[mb] = e; mb2row[mb] = acc + b * BM; ++mb; }
      acc += nb * BM;
    }
    off[E_EXP] = acc;
    for (; mb < MAXMB; ++mb) mb2e[mb] = -1;
  }
}

// ---------------- assign: wave ballot-rank + block LDS aggregation ----------------
__global__ __launch_bounds__(256) void assign_kernel(const int* __restrict__ tok_e,
                                                     const int* __restrict__ off,
                                                     int* __restrict__ fill,
                                                     int* __restrict__ perm,
                                                     int* __restrict__ tok_slot) {
  __shared__ int wcnt[4][E_EXP];
  __shared__ int wbase[4][E_EXP];
  const int tid = threadIdx.x, lane = tid & 63, wid = tid >> 6;
  if (tid < 32) wcnt[tid >> 3][tid & 7] = 0;
  __syncthreads();
  const int ent = blockIdx.x * 256 + tid;          // ent = 2*t + k
  const int e = tok_e[ent];
  int myrank = 0;
#pragma unroll
  for (int e0 = 0; e0 < E_EXP; ++e0) {
    unsigned long long m = __ballot(e == e0);
    if (e == e0) {
      myrank = __popcll(m & ((1ull << lane) - 1ull));
      if (myrank == 0) wcnt[wid][e0] = __popcll(m);
    }
  }
  __syncthreads();
  if (tid < E_EXP) {
    int tot = wcnt[0][tid] + wcnt[1][tid] + wcnt[2][tid] + wcnt[3][tid];
    int base = tot ? atomicAdd(&fill[tid], tot) : 0;
#pragma unroll
    for (int w = 0; w < 4; ++w) { wbase[w][tid] = base; base += wcnt[w][tid]; }
  }
  __syncthreads();
  const int slot = off[e] + wbase[wid][e] + myrank;
  perm[slot] = ent >> 1;
  tok_slot[ent] = slot;
}

// ---------------- gather tokens -> contiguous bf16 rows per expert ----------------
__global__ __launch_bounds__(128) void gather_kernel(const float* __restrict__ x,
                                                     const int* __restrict__ off,
                                                     const int* __restrict__ counts,
                                                     const int* __restrict__ perm,
                                                     short* __restrict__ Xp) {
  int s = blockIdx.x, tid = threadIdx.x;
  int e = -1;
#pragma unroll
  for (int i = 0; i < E_EXP; ++i)
    if (s >= off[i] && s < off[i + 1]) { e = i; break; }
  bool valid = false; int t = 0;
  if (e >= 0) { int r = s - off[e]; if (r < counts[e]) { valid = true; t = perm[s]; } }
  s16x8 o;
  if (valid) {
    const f32x4* xr = (const f32x4*)(x + (size_t)t * D_DIM);
    f32x4 a = xr[tid * 2], b = xr[tid * 2 + 1];
    o[0] = bf16_of(a[0]); o[1] = bf16_of(a[1]); o[2] = bf16_of(a[2]); o[3] = bf16_of(a[3]);
    o[4] = bf16_of(b[0]); o[5] = bf16_of(b[1]); o[6] = bf16_of(b[2]); o[7] = bf16_of(b[3]);
  } else {
#pragma unroll
    for (int j = 0; j < 8; ++j) o[j] = 0;
  }
  *(s16x8*)(Xp + (size_t)s * D_DIM + tid * 8) = o;
}

// ---------------- GEMM with FUSED fp32->bf16 B-conversion ----------------
// 256x256 tile, BK=64, dbuf-2 128KB LDS, R8-proven loose schedule (one
// vmcnt(0)+barrier per K64-tile). A: bf16 via global_load_lds (prefetch-1,
// row&7 slot swizzle, pre-swizzled source — rule 21). B: fp32 weights loaded
// to regs at tile top (T14 issue-early), converted + swizzled ds_write at tile
// end inside the existing drain window. LDS B content is bitwise identical to
// the old conv_w12/conv_w3 output, so the read side is unchanged from R8.
// EPI=0: Bw1/Bw2 = w1/w2 fp32, 16-row interleave; epilogue h=(a1+b1)*silu(a2+b2).
// EPI=1: Bw1 = w3 fp32 (identity rows); epilogue y = acc + b3.
template <int K, int EPI>
__global__ __launch_bounds__(512, 2)
void gemm_fb(const short* __restrict__ A,
             const float* __restrict__ Bw1,
             const float* __restrict__ Bw2,
             const int* __restrict__ mb2e,
             const int* __restrict__ mb2row,
             const float* __restrict__ biasA,
             const float* __restrict__ biasB,
             short* __restrict__ Out) {
  constexpr int KB = K * 2;          // A row bytes (bf16)
  constexpr int NT = K / 64;         // K64-tiles
  constexpr int HBYTES = 32768;      // one operand tile: 256 rows x 128B
  constexpr int BUFB = 2 * HBYTES;   // A + B
  constexpr int BSRCLD = (EPI == 0) ? D_DIM : H_DIM;   // fp32 B row length

  const int mb = blockIdx.y;
  const int e = mb2e[mb];
  if (e < 0) return;
  const int row0 = mb2row[mb];
  const int bn = blockIdx.x;

  __shared__ alignas(16) char lds[2 * BUFB];       // 128 KiB

  const int tid = threadIdx.x;
  const int lane = tid & 63;
  const int wid = tid >> 6;
  const int wr = wid >> 2;           // 0..1  (128-row half)
  const int wc = wid & 3;            // 0..3  (64-col quarter)

  const char* gA = (const char*)(A + (size_t)row0 * K);

  // ---- B source row pointer for this thread (row = tid>>1, k-half = tid&1) ----
  const int browS = tid >> 1, bh = tid & 1;
  const float* bsrc;
  if constexpr (EPI == 0) {
    const int np = bn * 256 + browS;               // interleaved n'
    const int half = (np >> 4) & 1;
    const int srow = (np >> 5) * 16 + (np & 15);
    bsrc = (half ? Bw2 : Bw1) + ((size_t)e * H_DIM + srow) * BSRCLD;
  } else {
    bsrc = Bw1 + ((size_t)e * D_DIM + bn * 256 + browS) * BSRCLD;
  }

  f32x4 br[8];                                     // 32 fp32 = this thread's B chunk

  auto loadB = [&](int kt) {                       // issue 8x16B global loads -> regs
    const f32x4* p = (const f32x4*)(bsrc + kt * 64 + bh * 32);
#pragma unroll
    for (int j = 0; j < 8; ++j) br[j] = p[j];
  };
  auto writeB = [&](int buf) {                     // cvt + 4 swizzled ds_write_b128
    char* l = lds + buf * BUFB + HBYTES + (size_t)browS * 128;
#pragma unroll
    for (int w = 0; w < 4; ++w) {
      const f32x4 a = br[2 * w], b = br[2 * w + 1];
      s16x8 o;
      o[0] = bf16_of(a[0]); o[1] = bf16_of(a[1]); o[2] = bf16_of(a[2]); o[3] = bf16_of(a[3]);
      o[4] = bf16_of(b[0]); o[5] = bf16_of(b[1]); o[6] = bf16_of(b[2]); o[7] = bf16_of(b[3]);
      const int s = bh * 4 + w;                    // logical 16B slot 0..7
      *(s16x8*)(l + ((s ^ (browS & 7)) * 16)) = o; // phys = logical ^ (row&7)
    }
  };
  auto stageA = [&](int kt, int buf) {             // 4 gload_lds, pre-swizzled src
#pragma unroll
    for (int r = 0; r < 4; ++r) {
      const int row = r * 64 + (tid >> 3);
      const int lq = (tid & 7) ^ (row & 7);
      gload16(gA + (size_t)row * KB + kt * 128 + lq * 16,
              lds + buf * BUFB + r * 8192 + tid * 16);
    }
  };

  f32x4 acc[8][4] = {};

  // prologue: tile 0 (A via gload_lds, B via regs); drain; write B0; barrier
  loadB(0);
  stageA(0, 0);
  asm volatile("s_waitcnt vmcnt(0)" ::: "memory");
  writeB(0);
  asm volatile("s_waitcnt lgkmcnt(0)" ::: "memory");
  __builtin_amdgcn_s_barrier();
  __builtin_amdgcn_sched_barrier(0);

  const int arow = wr * 128 + (lane & 15);
  const int brow = wc * 64 + (lane & 15);
  const int lsw = lane & 7;

  for (int t = 0; t < NT; ++t) {
    const char* bufb = lds + (t & 1) * BUFB;
    const int nb = (t + 1) & 1;
    const bool more = (t + 1 < NT);
    if (more) loadB(t + 1);                        // issue-early (T14)
#pragma unroll
    for (int ks = 0; ks < 2; ++ks) {
      const int q = ((ks * 4 + (lane >> 4)) ^ lsw) * 16;   // swizzled 16B slot
      s16x8 av[4], bv[4];
#pragma unroll
      for (int f = 0; f < 4; ++f)
        bv[f] = *(const s16x8*)(bufb + HBYTES + (size_t)(brow + f * 16) * 128 + q);
#pragma unroll
      for (int f = 0; f < 4; ++f)
        av[f] = *(const s16x8*)(bufb + (size_t)(arow + f * 16) * 128 + q);
      if (more && ks == 0) stageA(t + 1, nb);
      __builtin_amdgcn_s_setprio(1);
#pragma unroll
      for (int mf = 0; mf < 4; ++mf)
#pragma unroll
        for (int nf = 0; nf < 4; ++nf)
          acc[mf][nf] = __builtin_amdgcn_mfma_f32_16x16x32_bf16(av[mf], bv[nf], acc[mf][nf], 0, 0, 0);
      __builtin_amdgcn_s_setprio(0);
#pragma unroll
      for (int f = 0; f < 4; ++f)
        av[f] = *(const s16x8*)(bufb + (size_t)(arow + 64 + f * 16) * 128 + q);
      __builtin_amdgcn_s_setprio(1);
#pragma unroll
      for (int mf = 0; mf < 4; ++mf)
#pragma unroll
        for (int nf = 0; nf < 4; ++nf)
          acc[4 + mf][nf] = __builtin_amdgcn_mfma_f32_16x16x32_bf16(av[mf], bv[nf], acc[4 + mf][nf], 0, 0, 0);
      __builtin_amdgcn_s_setprio(0);
    }
    if (more) {
      __builtin_amdgcn_sched_barrier(0);
      asm volatile("s_waitcnt vmcnt(0)" ::: "memory");   // A(t+1) in LDS, br landed
      writeB(nb);                                        // cvt + write B(t+1)
      asm volatile("s_waitcnt lgkmcnt(0)" ::: "memory");
      __builtin_amdgcn_s_barrier();
      __builtin_amdgcn_sched_barrier(0);
    }
  }

  // epilogue: C/D layout col=lane&15, row=(lane>>4)*4+j
  if constexpr (EPI == 0) {
#pragma unroll
    for (int mf = 0; mf < 8; ++mf) {
      const int mrow = row0 + wr * 128 + mf * 16 + ((lane >> 4) << 2);
#pragma unroll
      for (int p = 0; p < 2; ++p) {                // nf pair: 2p=w1-path, 2p+1=w2-path
        const int hcol = bn * 128 + wc * 32 + p * 16 + (lane & 15);
        const float bb1 = biasA[e * H_DIM + hcol];
        const float bb2 = biasB[e * H_DIM + hcol];
        const f32x4 a1 = acc[mf][2 * p], a2 = acc[mf][2 * p + 1];
#pragma unroll
        for (int j = 0; j < 4; ++j) {
          float x1 = a1[j] + bb1, x2 = a2[j] + bb2;
          float hv = x1 * (x2 / (1.f + __expf(-x2)));   // x1 * silu(x2)
          Out[(size_t)(mrow + j) * H_DIM + hcol] = bf16_of(hv);
        }
      }
    }
  } else {
#pragma unroll
    for (int mf = 0; mf < 8; ++mf) {
      const int mrow = row0 + wr * 128 + mf * 16 + ((lane >> 4) << 2);
#pragma unroll
      for (int nf = 0; nf < 4; ++nf) {
        const int col = bn * 256 + wc * 64 + nf * 16 + (lane & 15);
        const float bb = biasA[e * D_DIM + col];
#pragma unroll
        for (int j = 0; j < 4; ++j)
          Out[(size_t)(mrow + j) * D_DIM + col] = bf16_of(acc[mf][nf][j] + bb);
      }
    }
  }
}

// ---------------- combine: out[t] = w0*ys[slot0] + w1*ys[slot1] ----------------
__global__ __launch_bounds__(128) void combine_kernel(const short* __restrict__ ysb,
                                                      const int* __restrict__ tok_slot,
                                                      const float* __restrict__ gatew,
                                                      float* __restrict__ out) {
  int t = blockIdx.x, tid = threadIdx.x;
  int s0 = tok_slot[2 * t], s1 = tok_slot[2 * t + 1];
  float w0 = gatew[2 * t], w1 = gatew[2 * t + 1];
  s16x8 a = *(const s16x8*)(ysb + (size_t)s0 * D_DIM + tid * 8);
  s16x8 b = *(const s16x8*)(ysb + (size_t)s1 * D_DIM + tid * 8);
  float* op = out + (size_t)t * D_DIM + tid * 8;
  f32x4 o0, o1;
#pragma unroll
  for (int j = 0; j < 4; ++j) o0[j] = w0 * f_of_bf16(a[j]) + w1 * f_of_bf16(b[j]);
#pragma unroll
  for (int j = 0; j < 4; ++j) o1[j] = w0 * f_of_bf16(a[4 + j]) + w1 * f_of_bf16(b[4 + j]);
  *(f32x4*)op = o0;
  *(f32x4*)(op + 4) = o1;
}

// ---------------- launcher ----------------
extern "C" void kernel_launch(void* const* d_in, const int* in_sizes, int n_in,
                              void* d_out, int out_size, void* d_ws, size_t ws_size,
                              hipStream_t stream) {
  const float* x  = (const float*)d_in[0];
  const float* gw = (const float*)d_in[1];
  const float* w1 = (const float*)d_in[2];
  const float* b1 = (const float*)d_in[3];
  const float* w2 = (const float*)d_in[4];
  const float* b2 = (const float*)d_in[5];
  const float* w3 = (const float*)d_in[6];
  const float* b3 = (const float*)d_in[7];
  float* out = (float*)d_out;

  char* ws = (char*)d_ws;
  size_t o = 0;
  short* Xp   = (short*)(ws + o); o += (size_t)CAP * D_DIM * 2;              //  37,748,736
  short* ysb  = Xp;                 // alias: Xp dead after gemm12, ysb written by gemm3
  short* hbuf = (short*)(ws + o); o += (size_t)CAP * H_DIM * 2;              //  75,497,472
  int* meta     = (int*)(ws + o);
  int* counts   = meta;             // 8
  int* fill     = meta + 8;         // 8
  int* offv     = meta + 16;        // 9 (pad to 16)
  int* mb2e     = meta + 32;        // 72 (pad to 80)
  int* mb2row   = meta + 112;       // 72 (pad to 80)
  int* tok_e    = meta + 192;       // 2T
  int* tok_slot = tok_e + 2 * T_TOK;
  int* perm     = tok_slot + 2 * T_TOK;             // CAP
  float* gatew  = (float*)(perm + CAP);             // 2T
  const size_t ws_needed = o + (192 + 4 * T_TOK + CAP + 2 * T_TOK) * sizeof(int);
  if (ws_size < ws_needed) return;   // fail validation loudly rather than corrupt

  hipMemsetAsync(counts, 0, 16 * sizeof(int), stream);  // counts + fill

  gate_kernel<<<T_TOK / 4, 256, 0, stream>>>(x, gw, tok_e, gatew);
  hist_kernel<<<(2 * T_TOK) / 1024, 256, 0, stream>>>(tok_e, counts);
  scan_kernel<<<1, 64, 0, stream>>>(counts, offv, mb2e, mb2row);
  assign_kernel<<<(2 * T_TOK) / 256, 256, 0, stream>>>(tok_e, offv, fill, perm, tok_slot);
  gather_kernel<<<CAP, 128, 0, stream>>>(x, offv, counts, perm, Xp);
  gemm_fb<D_DIM, 0><<<dim3(NP2 / 256, MAXMB), 512, 0, stream>>>(
      Xp, w1, w2, mb2e, mb2row, b1, b2, hbuf);
  gemm_fb<H_DIM, 1><<<dim3(D_DIM / 256, MAXMB), 512, 0, stream>>>(
      hbuf, w3, nullptr, mb2e, mb2row, b3, b3, ysb);
  combine_kernel<<<T_TOK, 128, 0, stream>>>(ysb, tok_slot, gatew, out);
}

// Round 10
// 378.145 us; speedup vs baseline: 1.4955x; 1.4955x over previous
//
#include <hip/hip_runtime.h>
#include <hip/hip_bf16.h>
#include <stdint.h>

// Problem constants: B=4,S=2048 -> T=8192, D=1024, H=2048, E=8, topk=2
#define T_TOK   8192
#define D_DIM   1024
#define H_DIM   2048
#define E_EXP   8
#define NP2     4096                    // interleaved w1/w2 rows = 2*H
#define BM      256                     // GEMM M/N tile; expert regions 256-aligned
#define CAP     (2*T_TOK + E_EXP*BM)    // 18432 padded slots
#define MAXMB   (CAP/BM)                // 72 max m-blocks

using f32x4 = __attribute__((ext_vector_type(4))) float;
using s16x4 = __attribute__((ext_vector_type(4))) short;
using s16x8 = __attribute__((ext_vector_type(8))) short;   // 8 bf16 (MFMA A/B frag)

__device__ __forceinline__ short bf16_of(float f) {
  union { float f; unsigned u; } v; v.f = f;
  unsigned r = v.u + 0x7FFFu + ((v.u >> 16) & 1u);          // RNE
  return (short)(r >> 16);
}
__device__ __forceinline__ float f_of_bf16(short s) {
  union { unsigned u; float f; } v; v.u = ((unsigned)(unsigned short)s) << 16;
  return v.f;
}

__device__ __forceinline__ void gload16(const void* g, void* l) {
  __builtin_amdgcn_global_load_lds(
      (const __attribute__((address_space(1))) unsigned int*)g,
      (__attribute__((address_space(3))) unsigned int*)l, 16, 0, 0);
}

// ---------------- weight conversion ----------------
// w12b layout: [e][n'][k], n' = g*32 + half*16 + s -> (half?w2:w1)[e][g*16+s][k]
__global__ __launch_bounds__(256) void conv_w12(const float* __restrict__ w1,
                                                const float* __restrict__ w2,
                                                short* __restrict__ w12b) {
  int idx = blockIdx.x * 256 + threadIdx.x;        // over E*4096*256 f32x4 units
  int e = idx >> 20;
  int rem = idx & 0xFFFFF;
  int np = rem >> 8;
  int kc = rem & 255;
  int g = np >> 5, tt = np & 31, half = tt >> 4, srow = g * 16 + (tt & 15);
  const f32x4* src = (const f32x4*)(half ? w2 : w1) + ((size_t)e * H_DIM + srow) * 256 + kc;
  f32x4 v = *src;
  s16x4 o;
  o[0] = bf16_of(v[0]); o[1] = bf16_of(v[1]); o[2] = bf16_of(v[2]); o[3] = bf16_of(v[3]);
  ((s16x4*)w12b)[idx] = o;
}

__global__ __launch_bounds__(256) void conv_w3(const float* __restrict__ w3,
                                               short* __restrict__ w3b) {
  int idx = blockIdx.x * 256 + threadIdx.x;        // over E*1024*512 f32x4 units
  f32x4 v = ((const f32x4*)w3)[idx];
  s16x4 o;
  o[0] = bf16_of(v[0]); o[1] = bf16_of(v[1]); o[2] = bf16_of(v[2]); o[3] = bf16_of(v[3]);
  ((s16x4*)w3b)[idx] = o;
}

// ---------------- gating (no atomics) ----------------
__global__ __launch_bounds__(256) void gate_kernel(const float* __restrict__ x,
                                                   const float* __restrict__ gw,
                                                   int* __restrict__ tok_e,
                                                   float* __restrict__ gatew) {
  __shared__ float g[E_EXP * D_DIM];               // 32 KiB
  int tid = threadIdx.x;
  for (int i = tid; i < E_EXP * 256; i += 256)
    ((f32x4*)g)[i] = ((const f32x4*)gw)[i];
  __syncthreads();
  int w = tid >> 6, lane = tid & 63;
  int t = blockIdx.x * 4 + w;
  float acc[E_EXP] = {};
  const f32x4* xrow = (const f32x4*)(x + (size_t)t * D_DIM);
#pragma unroll
  for (int i = 0; i < 4; ++i) {
    f32x4 xv = xrow[lane + 64 * i];
#pragma unroll
    for (int e = 0; e < E_EXP; ++e) {
      f32x4 gv = ((const f32x4*)g)[e * 256 + lane + 64 * i];
      acc[e] += xv[0] * gv[0] + xv[1] * gv[1] + xv[2] * gv[2] + xv[3] * gv[3];
    }
  }
#pragma unroll
  for (int e = 0; e < E_EXP; ++e)
#pragma unroll
    for (int off = 1; off < 64; off <<= 1)
      acc[e] += __shfl_xor(acc[e], off);
  if (lane == 0) {
    int i0 = 0; float v0 = acc[0];
    for (int e = 1; e < E_EXP; ++e) if (acc[e] > v0) { v0 = acc[e]; i0 = e; }  // ties: lower idx
    int i1 = -1; float v1 = -1e30f;
    for (int e = 0; e < E_EXP; ++e) if (e != i0 && acc[e] > v1) { v1 = acc[e]; i1 = e; }
    float z = __expf(v1 - v0);
    tok_e[2 * t] = i0; tok_e[2 * t + 1] = i1;
    gatew[2 * t] = 1.f / (1.f + z); gatew[2 * t + 1] = z / (1.f + z);
  }
}

// ---------------- histogram: ballot -> LDS -> 8 atomics/block ----------
__global__ __launch_bounds__(256) void hist_kernel(const int* __restrict__ tok_e,
                                                   int* __restrict__ counts) {
  __shared__ int bc[E_EXP];
  const int tid = threadIdx.x, lane = tid & 63;
  if (tid < E_EXP) bc[tid] = 0;
  __syncthreads();
  const int4 v = ((const int4*)tok_e)[blockIdx.x * 256 + tid];   // 4 entries/thread
#pragma unroll
  for (int e = 0; e < E_EXP; ++e) {
    int cnt = __popcll(__ballot(v.x == e)) + __popcll(__ballot(v.y == e)) +
              __popcll(__ballot(v.z == e)) + __popcll(__ballot(v.w == e));
    if (lane == 0 && cnt) atomicAdd(&bc[e], cnt);
  }
  __syncthreads();
  if (tid < E_EXP && bc[tid]) atomicAdd(&counts[tid], bc[tid]);
}

// ---------------- routing metadata ----------------
__global__ void scan_kernel(const int* __restrict__ counts, int* __restrict__ off,
                            int* __restrict__ mb2e, int* __restrict__ mb2row) {
  if (threadIdx.x == 0 && blockIdx.x == 0) {
    int acc = 0, mb = 0;
    for (int e = 0; e < E_EXP; ++e) {
      off[e] = acc;
      int nb = (counts[e] + BM - 1) / BM;
      for (int b = 0; b < nb; ++b) { mb2e[mb] = e; mb2row[mb] = acc + b * BM; ++mb; }
      acc += nb * BM;
    }
    off[E_EXP] = acc;
    for (; mb < MAXMB; ++mb) mb2e[mb] = -1;
  }
}

// ---------------- assign: wave ballot-rank + block LDS aggregation ----------------
__global__ __launch_bounds__(256) void assign_kernel(const int* __restrict__ tok_e,
                                                     const int* __restrict__ off,
                                                     int* __restrict__ fill,
                                                     int* __restrict__ perm,
                                                     int* __restrict__ tok_slot) {
  __shared__ int wcnt[4][E_EXP];
  __shared__ int wbase[4][E_EXP];
  const int tid = threadIdx.x, lane = tid & 63, wid = tid >> 6;
  if (tid < 32) wcnt[tid >> 3][tid & 7] = 0;
  __syncthreads();
  const int ent = blockIdx.x * 256 + tid;          // ent = 2*t + k
  const int e = tok_e[ent];
  int myrank = 0;
#pragma unroll
  for (int e0 = 0; e0 < E_EXP; ++e0) {
    unsigned long long m = __ballot(e == e0);
    if (e == e0) {
      myrank = __popcll(m & ((1ull << lane) - 1ull));
      if (myrank == 0) wcnt[wid][e0] = __popcll(m);
    }
  }
  __syncthreads();
  if (tid < E_EXP) {
    int tot = wcnt[0][tid] + wcnt[1][tid] + wcnt[2][tid] + wcnt[3][tid];
    int base = tot ? atomicAdd(&fill[tid], tot) : 0;
#pragma unroll
    for (int w = 0; w < 4; ++w) { wbase[w][tid] = base; base += wcnt[w][tid]; }
  }
  __syncthreads();
  const int slot = off[e] + wbase[wid][e] + myrank;
  perm[slot] = ent >> 1;
  tok_slot[ent] = slot;
}

// ---------------- gather tokens -> contiguous bf16 rows per expert ----------------
__global__ __launch_bounds__(128) void gather_kernel(const float* __restrict__ x,
                                                     const int* __restrict__ off,
                                                     const int* __restrict__ counts,
                                                     const int* __restrict__ perm,
                                                     short* __restrict__ Xp) {
  int s = blockIdx.x, tid = threadIdx.x;
  int e = -1;
#pragma unroll
  for (int i = 0; i < E_EXP; ++i)
    if (s >= off[i] && s < off[i + 1]) { e = i; break; }
  bool valid = false; int t = 0;
  if (e >= 0) { int r = s - off[e]; if (r < counts[e]) { valid = true; t = perm[s]; } }
  s16x8 o;
  if (valid) {
    const f32x4* xr = (const f32x4*)(x + (size_t)t * D_DIM);
    f32x4 a = xr[tid * 2], b = xr[tid * 2 + 1];
    o[0] = bf16_of(a[0]); o[1] = bf16_of(a[1]); o[2] = bf16_of(a[2]); o[3] = bf16_of(a[3]);
    o[4] = bf16_of(b[0]); o[5] = bf16_of(b[1]); o[6] = bf16_of(b[2]); o[7] = bf16_of(b[3]);
  } else {
#pragma unroll
    for (int j = 0; j < 8; ++j) o[j] = 0;
  }
  *(s16x8*)(Xp + (size_t)s * D_DIM + tid * 8) = o;
}

// ---------------- GEMM: 256x256 tile, BK=32, 8 waves, triple-buffer LDS,
// prefetch distance 2 K-tiles, counted vmcnt(4) per K-tile boundary (T3+T4).
// R3-proven LOOSE schedule: ONE barrier per K-tile; waves drift so one wave's
// MFMA covers another's ds_read/stage. Session ledger: lockstep (R4: -25µs),
// 4-phase (R6: -7µs), BK=64 (R8: -3µs), fused-B-cvt (R9: -160µs) all regressed.
template <int K, int EPI>
__global__ __launch_bounds__(512) void gemm256(const short* __restrict__ A,
                                               const short* __restrict__ Bw,
                                               const int* __restrict__ mb2e,
                                               const int* __restrict__ mb2row,
                                               const float* __restrict__ biasA,
                                               const float* __restrict__ biasB,
                                               short* __restrict__ Out) {
  constexpr int NFULL = (EPI == 0) ? NP2 : D_DIM;
  constexpr int OUTLD = (EPI == 0) ? H_DIM : D_DIM;
  constexpr int KB = K * 2;          // row bytes
  constexpr int NT = K / 32;         // K-tiles

  const int mb = blockIdx.y;
  const int e = mb2e[mb];
  if (e < 0) return;
  const int row0 = mb2row[mb];
  const int bn = blockIdx.x;

  __shared__ alignas(16) char lds[3 * 32768];      // 96 KiB: 3 bufs x (A 16K | B 16K)

  const int tid = threadIdx.x;
  const int lane = tid & 63;
  const int wid = tid >> 6;          // 0..7
  const int wr = wid >> 2;           // 0..1  (128-row half)
  const int wc = wid & 3;            // 0..3  (64-col quarter)

  const char* gA = (const char*)(A + (size_t)row0 * K);
  const char* gB = (const char*)(Bw + ((size_t)e * NFULL + (size_t)bn * BM) * K);

  const int srow0 = tid >> 2, spq = tid & 3;

  f32x4 acc[8][4] = {};

  auto stage = [&](int kt, int buf, int which) {   // which: 0=A, 1=B
    const char* g = which ? gB : gA;
    char* l = lds + buf * 32768 + which * 16384;
#pragma unroll
    for (int rnd = 0; rnd < 2; ++rnd) {
      const int row = rnd * 128 + srow0;
      const int lq = spq ^ ((row >> 1) & 3);
      gload16(g + (size_t)row * KB + kt * 64 + lq * 16,
              l + rnd * 8192 + tid * 16);          // = row*64 + spq*16 (linear dest)
    }
  };

  // prologue: stage tiles 0 and 1 (8 loads/thread), wait tile0's 4, barrier
  stage(0, 0, 0); stage(0, 0, 1);
  stage(1, 1, 0); stage(1, 1, 1);
  asm volatile("s_waitcnt vmcnt(4)" ::: "memory");
  __builtin_amdgcn_s_barrier();
  __builtin_amdgcn_sched_barrier(0);

  const int qsw = (((lane >> 4) ^ ((lane >> 1) & 3)) << 4);  // swizzled quarter byte
  const int arow = wr * 128 + (lane & 15);
  const int brow = wc * 64 + (lane & 15);

  int bc = 0;   // t % 3
  int b2 = 2;   // (t+2) % 3
  for (int t = 0; t < NT; ++t) {
    const char* bufb = lds + bc * 32768;
    const char* pa = bufb + arow * 64 + qsw;
    const char* pb = bufb + 16384 + brow * 64 + qsw;
    s16x8 av[4], bv[4];
#pragma unroll
    for (int f = 0; f < 4; ++f) bv[f] = *(const s16x8*)(pb + f * 1024);
#pragma unroll
    for (int f = 0; f < 4; ++f) av[f] = *(const s16x8*)(pa + f * 1024);
    if (t + 2 < NT) stage(t + 2, b2, 0);
    __builtin_amdgcn_s_setprio(1);
#pragma unroll
    for (int mf = 0; mf < 4; ++mf)
#pragma unroll
      for (int nf = 0; nf < 4; ++nf)
        acc[mf][nf] = __builtin_amdgcn_mfma_f32_16x16x32_bf16(av[mf], bv[nf], acc[mf][nf], 0, 0, 0);
    __builtin_amdgcn_s_setprio(0);
#pragma unroll
    for (int f = 0; f < 4; ++f) av[f] = *(const s16x8*)(pa + (4 + f) * 1024);
    if (t + 2 < NT) stage(t + 2, b2, 1);
    __builtin_amdgcn_s_setprio(1);
#pragma unroll
    for (int mf = 0; mf < 4; ++mf)
#pragma unroll
      for (int nf = 0; nf < 4; ++nf)
        acc[4 + mf][nf] = __builtin_amdgcn_mfma_f32_16x16x32_bf16(av[mf], bv[nf], acc[4 + mf][nf], 0, 0, 0);
    __builtin_amdgcn_s_setprio(0);

    if (t < NT - 1) {
      __builtin_amdgcn_sched_barrier(0);
      if (t == NT - 2) asm volatile("s_waitcnt vmcnt(0)" ::: "memory");
      else             asm volatile("s_waitcnt vmcnt(4)" ::: "memory");
      __builtin_amdgcn_s_barrier();
      __builtin_amdgcn_sched_barrier(0);
    }
    bc = (bc == 2) ? 0 : bc + 1;
    b2 = (b2 == 2) ? 0 : b2 + 1;
  }

  // epilogue: C/D layout col=lane&15, row=(lane>>4)*4+j
  if constexpr (EPI == 0) {
#pragma unroll
    for (int mf = 0; mf < 8; ++mf) {
      const int mrow = row0 + wr * 128 + mf * 16 + ((lane >> 4) << 2);
#pragma unroll
      for (int p = 0; p < 2; ++p) {                // nf pair: 2p=w1-path, 2p+1=w2-path
        const int hcol = bn * 128 + wc * 32 + p * 16 + (lane & 15);
        const float bb1 = biasA[e * H_DIM + hcol];
        const float bb2 = biasB[e * H_DIM + hcol];
        const f32x4 a1 = acc[mf][2 * p], a2 = acc[mf][2 * p + 1];
#pragma unroll
        for (int j = 0; j < 4; ++j) {
          float x1 = a1[j] + bb1, x2 = a2[j] + bb2;
          float hv = x1 * (x2 / (1.f + __expf(-x2)));   // x1 * silu(x2)
          Out[(size_t)(mrow + j) * OUTLD + hcol] = bf16_of(hv);
        }
      }
    }
  } else {
#pragma unroll
    for (int mf = 0; mf < 8; ++mf) {
      const int mrow = row0 + wr * 128 + mf * 16 + ((lane >> 4) << 2);
#pragma unroll
      for (int nf = 0; nf < 4; ++nf) {
        const int col = bn * BM + wc * 64 + nf * 16 + (lane & 15);
        const float bb = biasA[e * D_DIM + col];
#pragma unroll
        for (int j = 0; j < 4; ++j)
          Out[(size_t)(mrow + j) * OUTLD + col] = bf16_of(acc[mf][nf][j] + bb);
      }
    }
  }
}

// ---------------- combine: out[t] = w0*ys[slot0] + w1*ys[slot1] ----------------
__global__ __launch_bounds__(128) void combine_kernel(const short* __restrict__ ysb,
                                                      const int* __restrict__ tok_slot,
                                                      const float* __restrict__ gatew,
                                                      float* __restrict__ out) {
  int t = blockIdx.x, tid = threadIdx.x;
  int s0 = tok_slot[2 * t], s1 = tok_slot[2 * t + 1];
  float w0 = gatew[2 * t], w1 = gatew[2 * t + 1];
  s16x8 a = *(const s16x8*)(ysb + (size_t)s0 * D_DIM + tid * 8);
  s16x8 b = *(const s16x8*)(ysb + (size_t)s1 * D_DIM + tid * 8);
  float* op = out + (size_t)t * D_DIM + tid * 8;
  f32x4 o0, o1;
#pragma unroll
  for (int j = 0; j < 4; ++j) o0[j] = w0 * f_of_bf16(a[j]) + w1 * f_of_bf16(b[j]);
#pragma unroll
  for (int j = 0; j < 4; ++j) o1[j] = w0 * f_of_bf16(a[4 + j]) + w1 * f_of_bf16(b[4 + j]);
  *(f32x4*)op = o0;
  *(f32x4*)(op + 4) = o1;
}

// ---------------- launcher ----------------
extern "C" void kernel_launch(void* const* d_in, const int* in_sizes, int n_in,
                              void* d_out, int out_size, void* d_ws, size_t ws_size,
                              hipStream_t stream) {
  const float* x  = (const float*)d_in[0];
  const float* gw = (const float*)d_in[1];
  const float* w1 = (const float*)d_in[2];
  const float* b1 = (const float*)d_in[3];
  const float* w2 = (const float*)d_in[4];
  const float* b2 = (const float*)d_in[5];
  const float* w3 = (const float*)d_in[6];
  const float* b3 = (const float*)d_in[7];
  float* out = (float*)d_out;

  char* ws = (char*)d_ws;
  size_t o = 0;
  short* w12b = (short*)(ws + o); o += (size_t)E_EXP * NP2 * D_DIM * 2;      //  67,108,864
  short* w3b  = (short*)(ws + o); o += (size_t)E_EXP * D_DIM * H_DIM * 2;    //  33,554,432
  short* Xp   = (short*)(ws + o); o += (size_t)CAP * D_DIM * 2;              //  37,748,736
  short* ysb  = Xp;                 // alias: Xp dead after gemm12, ysb written by gemm3
  short* hbuf = (short*)(ws + o); o += (size_t)CAP * H_DIM * 2;              //  75,497,472
  int* meta     = (int*)(ws + o);
  int* counts   = meta;             // 8
  int* fill     = meta + 8;         // 8
  int* offv     = meta + 16;        // 9 (pad to 16)
  int* mb2e     = meta + 32;        // 72 (pad to 80)
  int* mb2row   = meta + 112;       // 72 (pad to 80)
  int* tok_e    = meta + 192;       // 2T
  int* tok_slot = tok_e + 2 * T_TOK;
  int* perm     = tok_slot + 2 * T_TOK;             // CAP
  float* gatew  = (float*)(perm + CAP);             // 2T
  const size_t ws_needed = o + (192 + 4 * T_TOK + CAP + 2 * T_TOK) * sizeof(int);
  if (ws_size < ws_needed) return;   // fail validation loudly rather than corrupt

  hipMemsetAsync(counts, 0, 16 * sizeof(int), stream);  // counts + fill

  conv_w12<<<(E_EXP * NP2 * 256) / 256, 256, 0, stream>>>(w1, w2, w12b);
  conv_w3 <<<(E_EXP * D_DIM * (H_DIM / 4)) / 256, 256, 0, stream>>>(w3, w3b);
  gate_kernel<<<T_TOK / 4, 256, 0, stream>>>(x, gw, tok_e, gatew);
  hist_kernel<<<(2 * T_TOK) / 1024, 256, 0, stream>>>(tok_e, counts);
  scan_kernel<<<1, 64, 0, stream>>>(counts, offv, mb2e, mb2row);
  assign_kernel<<<(2 * T_TOK) / 256, 256, 0, stream>>>(tok_e, offv, fill, perm, tok_slot);
  gather_kernel<<<CAP, 128, 0, stream>>>(x, offv, counts, perm, Xp);
  gemm256<D_DIM, 0><<<dim3(NP2 / BM, MAXMB), 512, 0, stream>>>(Xp, w12b, mb2e, mb2row, b1, b2, hbuf);
  gemm256<H_DIM, 1><<<dim3(D_DIM / BM, MAXMB), 512, 0, stream>>>(hbuf, w3b, mb2e, mb2row, b3, b3, ysb);
  combine_kernel<<<T_TOK, 128, 0, stream>>>(ysb, tok_slot, gatew, out);
}